// Round 8
// baseline (178.077 us; speedup 1.0000x reference)
//
#include <hip/hip_runtime.h>
#include <hip/hip_bf16.h>

// AdaBiD R7b (resubmit; R7 died to container infra twice - only delta is
// dropping the occupancy-forcing __launch_bounds__ second arg on fused_mlp).
// 3-kernel pipeline. MI355X gfx950.
// B=8, T=12, N=1536, H=64, TH=768, HID2=128, T_OUT=12.
//  K1 prep_all: role by blockIdx: [0,48) softmax/logp/self-dot + frag arrays
//               (b-frags PACKED per row: [lhi|llo|phi|plo] -> 1 cache line),
//               [48,146) weight repack -> B-frag order, 146 smalls + flag.
//  K2 kl_mfma:  flash-style KL threshold + bidirectional aggregation via
//               split-bf16 MFMA; 8-way j-split partials. Packed b-frag loads.
//  K3 fused_mlp: 512-thr blocks, TWO 16-row tiles per block (4 waves each):
//               half the per-block weight traffic (both tile-groups stream
//               identical weights -> L1/L2 reuse). kl-partial reduce + all 6
//               MLP layers + transposed store, barriers at phase boundaries.

namespace {

constexpr int Bn = 8, Nn = 1536, TOUT = 12;
constexpr int Mrows = Bn * Nn;   // 12288
constexpr int JS = 8;            // j-split in kl

typedef __attribute__((ext_vector_type(8))) short bf8;
typedef __attribute__((ext_vector_type(4))) float f4;
typedef unsigned short ush;

__device__ __forceinline__ float b2f(__hip_bfloat16 v) { return __bfloat162float(v); }
__device__ __forceinline__ ush f2bu(float f) {
  union { __hip_bfloat16 h; ush u; } c; c.h = __float2bfloat16(f); return c.u;
}
__device__ __forceinline__ float bu2f(ush u) {
  union { unsigned int i; float f; } c; c.i = ((unsigned)u) << 16; return c.f;
}
__device__ __forceinline__ float ldraw(const void* p, size_t i, int fl) {
  return fl ? ((const float*)p)[i] : b2f(((const __hip_bfloat16*)p)[i]);
}

// block-local dtype sniff: bf16 N(0,1) never has exp-field >= 140; f32 read
// as ushorts has ~45% of low-halves >= 140.  4096 samples.
__device__ __forceinline__ int detect_fl(const void* x, int tid) {
  __shared__ int cnt;
  if (tid == 0) cnt = 0;
  __syncthreads();
  const ush* u = (const ush*)x;
  int c = 0;
#pragma unroll
  for (int s = 0; s < 16; ++s) {
    ush v = u[tid + s * 256];
    if (((v >> 7) & 0xFF) >= 140) c++;
  }
  atomicAdd(&cnt, c);
  __syncthreads();
  return (cnt > 64) ? 1 : 0;
}

struct SmallTab { const void* src[16]; int n[16]; int off[16]; };
struct RepTab { const void* src[8]; int Nc[8]; int NCT[8]; int lb[9]; };

// ---------------- K1: prep + repack + smalls ---------------------------------
__global__ __launch_bounds__(256) void prep_all(
    const void* __restrict__ xraw, SmallTab st, RepTab rt,
    int* __restrict__ flag, float* __restrict__ CS,
    float* __restrict__ xT, float* __restrict__ sd,
    ush* __restrict__ pA, ush* __restrict__ lA,
    ush* __restrict__ Pk, ush* __restrict__ Xc, ush* __restrict__ Wf) {
  int tid = threadIdx.x;
  int fl = detect_fl(xraw, tid);
  int blk = blockIdx.x;

  if (blk < 48) {
    // ---- prep role: one thread per (b,n) row ----
    int row = blk * 256 + tid;
    int b = row / Nn, n = row - b * Nn;
    float xv[12];
#pragma unroll
    for (int t = 0; t < 12; ++t)
      xv[t] = ldraw(xraw, (size_t)(b * 12 + t) * Nn + n, fl);
    float mx = xv[0];
#pragma unroll
    for (int t = 1; t < 12; ++t) mx = fmaxf(mx, xv[t]);
    float e[12], Z = 0.f;
#pragma unroll
    for (int t = 0; t < 12; ++t) { e[t] = expf(xv[t] - mx); Z += e[t]; }
    float invZ = 1.f / Z;
    float sacc = 0.f;
    ush pa[32], la[32], pk[64];
#pragma unroll
    for (int k = 0; k < 32; ++k) { pa[k] = 0; la[k] = 0; }
#pragma unroll
    for (int k = 0; k < 64; ++k) pk[k] = 0;
#pragma unroll
    for (int t = 0; t < 12; ++t) {
      float pv = e[t] * invZ;
      float lv = logf(pv + 1e-10f);
      sacc += pv * lv;
      xT[(size_t)row * 12 + t] = xv[t];
      ush phv = f2bu(pv);  float plv = pv - bu2f(phv);
      ush lhv = f2bu(lv);  float llv = lv - bu2f(lhv);
      pa[t] = phv; pa[16 + t] = f2bu(plv);
      la[t] = lhv; la[16 + t] = f2bu(llv);
      pk[t] = lhv;            // [0:16)  lhi
      pk[16 + t] = f2bu(llv); // [16:32) llo
      pk[32 + t] = phv;       // [32:48) phi
      pk[48 + t] = f2bu(plv); // [48:64) plo
      Xc[((size_t)(b * 16 + t)) * Nn + n] = f2bu(xv[t]);
    }
    Xc[((size_t)(b * 16 + 12)) * Nn + n] = 0x3F80;  // ones col -> degrees
#pragma unroll
    for (int t = 13; t < 16; ++t) Xc[((size_t)(b * 16 + t)) * Nn + n] = 0;
    sd[row] = sacc;
    {
      uint4* d = (uint4*)(pA + (size_t)row * 32);
      const uint4* s = (const uint4*)pa;
      d[0] = s[0]; d[1] = s[1]; d[2] = s[2]; d[3] = s[3];
      uint4* d2 = (uint4*)(lA + (size_t)row * 32);
      const uint4* s2 = (const uint4*)la;
      d2[0] = s2[0]; d2[1] = s2[1]; d2[2] = s2[2]; d2[3] = s2[3];
      uint4* d3 = (uint4*)(Pk + (size_t)row * 64);
      const uint4* s3 = (const uint4*)pk;
#pragma unroll
      for (int v = 0; v < 8; ++v) d3[v] = s3[v];
    }
  } else if (blk < 146) {
    // ---- repack role: weights -> MFMA B-frag order ----
    int idx = (blk - 48) * 256 + tid;
    if (idx >= rt.lb[8]) return;
    int mi = 0;
#pragma unroll
    for (int i = 1; i < 8; ++i) if (idx >= rt.lb[i]) mi = i;
    int li = idx - rt.lb[mi];
    int NCT = rt.NCT[mi], Nc = rt.Nc[mi];
    int per = NCT * 64;
    int c0 = li / per, rem = li - c0 * per;
    int ct = rem >> 6, l = rem & 63;
    int q = l >> 4, m = l & 15;
    int col = ct * 16 + m;
    ush* d = Wf + (size_t)idx * 8;
#pragma unroll
    for (int j = 0; j < 8; ++j) {
      int k = c0 * 32 + q * 8 + j;
      d[j] = (col < Nc) ? f2bu(ldraw(rt.src[mi], (size_t)k * Nc + col, fl)) : 0;
    }
  } else {
    // ---- smalls role: canonicalize biases/BN params + publish flag ----
    for (int i = 0; i < 16; ++i)
      for (int e = tid; e < st.n[i]; e += 256)
        CS[st.off[i] + e] = ldraw(st.src[i], e, fl);
    if (tid == 0) flag[0] = fl;
  }
}

// ---------------- K2: kl via MFMA (flash-style) ------------------------------
// Block 256 = 4 waves; wave owns a 16-row i-tile, loops 12 j-tiles of split js.
// S1 = p_i . lp_j via split-bf16 (hi/lo), S2 = lp_i . p_j likewise.
// A1=(self_i-S1<.5)=A[i,j], A2=(self_j-S2<.5)=A[j,i]; aggregate both against
// X' (cols 0..11 = x, col 12 = ones -> row/col degrees). Wave-private LDS
// roundtrip converts the 0/1 mask from C-layout to A-frag layout.
// b-frags come from the packed per-row [lhi|llo|phi|plo] line (Pk).
__global__ __launch_bounds__(256) void kl_mfma(
    const ush* __restrict__ pA, const ush* __restrict__ lA,
    const ush* __restrict__ Pk, const ush* __restrict__ Xc,
    const float* __restrict__ sd,
    float* __restrict__ psf, float* __restrict__ psb) {
  __shared__ ush T1[4][512], T2[4][512];
  int tid = threadIdx.x, w = tid >> 6, l = tid & 63, q = l >> 4, n = l & 15;
  int blk = blockIdx.x;
  int b = blk / 192, rem = blk % 192, ig = rem >> 3, js = rem & 7;
  int i0 = ig * 64 + w * 16;
  int rowb = b * Nn;

  if (q >= 2) {  // zero the k>=16 pad of the mask frags once
    uint4 z4 = {0, 0, 0, 0};
    *(uint4*)(&T1[w][(size_t)l * 8]) = z4;
    *(uint4*)(&T2[w][(size_t)l * 8]) = z4;
  }

  bf8 z8 = {0, 0, 0, 0, 0, 0, 0, 0};
  bf8 aP = *(const bf8*)(pA + ((size_t)(rowb + i0 + n)) * 32 + q * 8);
  bf8 aL = *(const bf8*)(lA + ((size_t)(rowb + i0 + n)) * 32 + q * 8);
  bf8 aPh = (q < 2) ? aP : z8;
  bf8 aLh = (q < 2) ? aL : z8;
  float selfI[4];
#pragma unroll
  for (int r = 0; r < 4; ++r) selfI[r] = sd[rowb + i0 + q * 4 + r];

  f4 accF = {0.f, 0.f, 0.f, 0.f}, accB = {0.f, 0.f, 0.f, 0.f};

  for (int jt = 0; jt < 12; ++jt) {
    int jl = js * 192 + jt * 16;
    const ush* pb = Pk + ((size_t)(rowb + jl + n)) * 64 + (q & 1) * 8;
    bf8 bLh = *(const bf8*)(pb);
    bf8 bLo = *(const bf8*)(pb + 16);
    bf8 bPh = *(const bf8*)(pb + 32);
    bf8 bPo = *(const bf8*)(pb + 48);
    float selfJ = sd[rowb + jl + n];

    f4 s1 = {0.f, 0.f, 0.f, 0.f}, s2 = {0.f, 0.f, 0.f, 0.f};
    s1 = __builtin_amdgcn_mfma_f32_16x16x32_bf16(aP, bLh, s1, 0, 0, 0);
    s1 = __builtin_amdgcn_mfma_f32_16x16x32_bf16(aPh, bLo, s1, 0, 0, 0);
    s2 = __builtin_amdgcn_mfma_f32_16x16x32_bf16(aL, bPh, s2, 0, 0, 0);
    s2 = __builtin_amdgcn_mfma_f32_16x16x32_bf16(aLh, bPo, s2, 0, 0, 0);

    int qk = n >> 3, kj = n & 7;
#pragma unroll
    for (int r = 0; r < 4; ++r) {
      int pos = (qk * 16 + q * 4 + r) * 8 + kj;
      T1[w][pos] = (selfI[r] - s1[r] < 0.5f) ? (ush)0x3F80 : (ush)0;
      T2[w][pos] = (selfJ - s2[r] < 0.5f) ? (ush)0x3F80 : (ush)0;
    }
    bf8 af1 = *(const bf8*)(&T1[w][(size_t)l * 8]);
    bf8 af2 = *(const bf8*)(&T2[w][(size_t)l * 8]);
    bf8 xfr = (q < 2)
        ? *(const bf8*)(Xc + ((size_t)(b * 16 + n)) * Nn + jl + q * 8) : z8;
    accF = __builtin_amdgcn_mfma_f32_16x16x32_bf16(af1, xfr, accF, 0, 0, 0);
    accB = __builtin_amdgcn_mfma_f32_16x16x32_bf16(af2, xfr, accB, 0, 0, 0);
  }
#pragma unroll
  for (int r = 0; r < 4; ++r) {
    size_t o = ((size_t)js * Mrows + rowb + i0 + q * 4 + r) * 16 + n;
    psf[o] = accF[r];
    psb[o] = accB[r];
  }
}

// ---------------- K3: fused MLP, 512 thr = 2 tiles x 4 waves -----------------
// LDS frag layout (lane-major): slot(c0, l)*8+j holds A[m=l&15][k=(l>>4)*8+j].
// Within a tile, wave ws_ handles col-tiles {2ws_,2ws_+1} for N=128 layers,
// {ws_} for N=64, K-split for the N=12 tail. Both tiles stream the same
// weights -> L1/L2 reuse. Barriers only at phase boundaries.
__global__ __launch_bounds__(512) void fused_mlp(
    const float* __restrict__ xT,
    const float* __restrict__ psf, const float* __restrict__ psb,
    const float* __restrict__ CS, const ush* __restrict__ Wf,
    const int* __restrict__ flag, void* __restrict__ outp) {
  __shared__ float xs[32][12], ccs[32][12];
  __shared__ float sfs[32][16], sbs[32][16];
  __shared__ float ws1[64], ws2[64];
  __shared__ ush hf[2][2048], hg[2][2048], xf[2][1024];
  __shared__ f4 red[2][4][64];

  int tid = threadIdx.x, w = tid >> 6, l = tid & 63, q = l >> 4, n = l & 15;
  int tile = w >> 2, ws_ = w & 3;
  int r0b = blockIdx.x * 32;       // block row base (2 tiles)
  int r0 = r0b + tile * 16;        // this wave-group's tile base

  // --- init: kl-partial reduce, W1/W2, xs ---------------------------------
  {
    int r = tid >> 4, t = tid & 15;   // 32 rows x 16 cols
    float a = 0.f, b = 0.f;
#pragma unroll
    for (int js = 0; js < JS; ++js) {
      size_t o = ((size_t)js * Mrows + r0b + r) * 16 + t;
      a += psf[o];
      b += psb[o];
    }
    sfs[r][t] = a;
    sbs[r][t] = b;
    if (tid < 128) { if (tid < 64) ws1[tid] = CS[tid]; else ws2[tid - 64] = CS[tid]; }
    if (tid < 384) {
      int rr = tid / 12, tt = tid - rr * 12;
      xs[rr][tt] = xT[(size_t)(r0b + rr) * 12 + tt];
    }
  }
  __syncthreads();
  if (tid < 384) {
    int rr = tid / 12, tt = tid - rr * 12;
    float irs = 1.f / fmaxf(sfs[rr][12], 1e-6f);
    float ics = 1.f / fmaxf(sbs[rr][12], 1e-6f);
    ccs[rr][tt] = 3.0f * (0.3f * sfs[rr][tt] * irs + 0.7f * sbs[rr][tt] * ics);
  }
  __syncthreads();

  // z A-frag regen: row = r0+n, k = c0*32 + q*8 + j
  auto zregen = [&](int c0) -> bf8 {
    int t = c0 >> 1, h0 = (c0 & 1) * 32 + q * 8;
    float xv = xs[tile * 16 + n][t], cv = ccs[tile * 16 + n][t];
    union { bf8 v; ush u[8]; } au;
#pragma unroll
    for (int j = 0; j < 8; ++j)
      au.u[j] = f2bu(fmaxf(fmaf(xv, ws1[h0 + j], cv * ws2[h0 + j]), 0.f));
    return au.v;
  };
  // C-layout -> frag-slot store position for col-tile ct (within tile buffer)
  auto fpos = [&](int ct, int r) -> int {
    return ((ct >> 1) * 64 + ((ct & 1) * 2 + (n >> 3)) * 16 + q * 4 + r) * 8 + (n & 7);
  };

  ush* hfT = hf[tile];
  ush* hgT = hg[tile];
  ush* xfT = xf[tile];

  // --- L1e: h1 = relu(z @ ew1 + b1), N=128, wave does ct = 2ws_, 2ws_+1 ----
  {
    f4 a0 = {0.f, 0.f, 0.f, 0.f}, a1 = {0.f, 0.f, 0.f, 0.f};
    for (int c0 = 0; c0 < 24; ++c0) {
      bf8 a = zregen(c0);
      const ush* wb = Wf + ((size_t)(c0 * 8 + 2 * ws_) * 64 + l) * 8;
      bf8 b0 = *(const bf8*)wb;
      bf8 b1 = *(const bf8*)(wb + 512);
      a0 = __builtin_amdgcn_mfma_f32_16x16x32_bf16(a, b0, a0, 0, 0, 0);
      a1 = __builtin_amdgcn_mfma_f32_16x16x32_bf16(a, b1, a1, 0, 0, 0);
    }
#pragma unroll
    for (int u2 = 0; u2 < 2; ++u2) {
      int ct = 2 * ws_ + u2;
      f4 acc = u2 ? a1 : a0;
      float bz = CS[128 + ct * 16 + n];
#pragma unroll
      for (int r = 0; r < 4; ++r)
        hfT[fpos(ct, r)] = f2bu(fmaxf(acc[r] + bz, 0.f));
    }
  }
  __syncthreads();

  // --- L2e: h2 = relu(h1 @ ew2 + b2), K=128 --------------------------------
  {
    f4 a0 = {0.f, 0.f, 0.f, 0.f}, a1 = {0.f, 0.f, 0.f, 0.f};
    for (int c0 = 0; c0 < 4; ++c0) {
      bf8 a = *(const bf8*)(&hfT[(size_t)(c0 * 64 + l) * 8]);
      const ush* wb = Wf + 98304 + ((size_t)(c0 * 8 + 2 * ws_) * 64 + l) * 8;
      bf8 b0 = *(const bf8*)wb;
      bf8 b1 = *(const bf8*)(wb + 512);
      a0 = __builtin_amdgcn_mfma_f32_16x16x32_bf16(a, b0, a0, 0, 0, 0);
      a1 = __builtin_amdgcn_mfma_f32_16x16x32_bf16(a, b1, a1, 0, 0, 0);
    }
#pragma unroll
    for (int u2 = 0; u2 < 2; ++u2) {
      int ct = 2 * ws_ + u2;
      f4 acc = u2 ? a1 : a0;
      float bz = CS[256 + ct * 16 + n];
#pragma unroll
      for (int r = 0; r < 4; ++r)
        hgT[fpos(ct, r)] = f2bu(fmaxf(acc[r] + bz, 0.f));
    }
  }
  __syncthreads();

  // --- L3e: xe = BN(h2 @ ew3 + b3 + z @ eproj), N=64, wave does ct = ws_ ---
  {
    f4 a3 = {0.f, 0.f, 0.f, 0.f};
    for (int c0 = 0; c0 < 4; ++c0) {
      bf8 a = *(const bf8*)(&hgT[(size_t)(c0 * 64 + l) * 8]);
      bf8 b = *(const bf8*)(Wf + 114688 + ((size_t)(c0 * 4 + ws_) * 64 + l) * 8);
      a3 = __builtin_amdgcn_mfma_f32_16x16x32_bf16(a, b, a3, 0, 0, 0);
    }
    for (int c0 = 0; c0 < 24; ++c0) {
      bf8 a = zregen(c0);
      bf8 b = *(const bf8*)(Wf + 122880 + ((size_t)(c0 * 4 + ws_) * 64 + l) * 8);
      a3 = __builtin_amdgcn_mfma_f32_16x16x32_bf16(a, b, a3, 0, 0, 0);
    }
    int col = ws_ * 16 + n;
    float g = CS[448 + col], be = CS[512 + col], mm = CS[576 + col], vv = CS[640 + col];
    float sc = g / sqrtf(vv + 1e-5f);
    float sh = be - mm * sc;
    float bz = CS[384 + col];
#pragma unroll
    for (int r = 0; r < 4; ++r)
      xfT[fpos(ws_, r)] = f2bu((a3[r] + bz) * sc + sh);
  }
  __syncthreads();

  // --- L1d: g1 = relu(xe @ dw1 + b1), K=64, N=128 --------------------------
  {
    f4 a0 = {0.f, 0.f, 0.f, 0.f}, a1 = {0.f, 0.f, 0.f, 0.f};
    for (int c0 = 0; c0 < 2; ++c0) {
      bf8 a = *(const bf8*)(&xfT[(size_t)(c0 * 64 + l) * 8]);
      const ush* wb = Wf + 172032 + ((size_t)(c0 * 8 + 2 * ws_) * 64 + l) * 8;
      bf8 b0 = *(const bf8*)wb;
      bf8 b1 = *(const bf8*)(wb + 512);
      a0 = __builtin_amdgcn_mfma_f32_16x16x32_bf16(a, b0, a0, 0, 0, 0);
      a1 = __builtin_amdgcn_mfma_f32_16x16x32_bf16(a, b1, a1, 0, 0, 0);
    }
#pragma unroll
    for (int u2 = 0; u2 < 2; ++u2) {
      int ct = 2 * ws_ + u2;
      f4 acc = u2 ? a1 : a0;
      float bz = CS[704 + ct * 16 + n];
#pragma unroll
      for (int r = 0; r < 4; ++r)
        hfT[fpos(ct, r)] = f2bu(fmaxf(acc[r] + bz, 0.f));
    }
  }
  __syncthreads();

  // --- L2d: g2 = relu(g1 @ dw2 + b2), K=128 --------------------------------
  {
    f4 a0 = {0.f, 0.f, 0.f, 0.f}, a1 = {0.f, 0.f, 0.f, 0.f};
    for (int c0 = 0; c0 < 4; ++c0) {
      bf8 a = *(const bf8*)(&hfT[(size_t)(c0 * 64 + l) * 8]);
      const ush* wb = Wf + 180224 + ((size_t)(c0 * 8 + 2 * ws_) * 64 + l) * 8;
      bf8 b0 = *(const bf8*)wb;
      bf8 b1 = *(const bf8*)(wb + 512);
      a0 = __builtin_amdgcn_mfma_f32_16x16x32_bf16(a, b0, a0, 0, 0, 0);
      a1 = __builtin_amdgcn_mfma_f32_16x16x32_bf16(a, b1, a1, 0, 0, 0);
    }
#pragma unroll
    for (int u2 = 0; u2 < 2; ++u2) {
      int ct = 2 * ws_ + u2;
      f4 acc = u2 ? a1 : a0;
      float bz = CS[832 + ct * 16 + n];
#pragma unroll
      for (int r = 0; r < 4; ++r)
        hgT[fpos(ct, r)] = f2bu(fmaxf(acc[r] + bz, 0.f));
    }
  }
  __syncthreads();

  // --- L3d: out = BN(g2 @ dw3 + b3 + xe @ dproj), N=12; K-split 4 waves ----
  {
    f4 ao = {0.f, 0.f, 0.f, 0.f};
    {  // dw3 chunk c0 = ws_  (K=128 -> 4 chunks)
      bf8 a = *(const bf8*)(&hgT[(size_t)(ws_ * 64 + l) * 8]);
      bf8 b = *(const bf8*)(Wf + 196608 + ((size_t)ws_ * 64 + l) * 8);
      ao = __builtin_amdgcn_mfma_f32_16x16x32_bf16(a, b, ao, 0, 0, 0);
    }
    if (ws_ < 2) {  // dproj chunk c0 = ws_  (K=64 -> 2 chunks)
      bf8 a = *(const bf8*)(&xfT[(size_t)(ws_ * 64 + l) * 8]);
      bf8 b = *(const bf8*)(Wf + 198656 + ((size_t)ws_ * 64 + l) * 8);
      ao = __builtin_amdgcn_mfma_f32_16x16x32_bf16(a, b, ao, 0, 0, 0);
    }
    red[tile][ws_][l] = ao;
  }
  __syncthreads();
  if (ws_ == 0) {
    f4 s = red[tile][0][l] + red[tile][1][l] + red[tile][2][l] + red[tile][3][l];
    int fl = flag[0];
    if (n < 12) {
      float bz = CS[960 + n];
      float g = CS[972 + n], be = CS[984 + n], mm = CS[996 + n], vv = CS[1008 + n];
      float sc = g / sqrtf(vv + 1e-5f);
      float sh = be - mm * sc;
#pragma unroll
      for (int r = 0; r < 4; ++r) {
        int row = r0 + q * 4 + r;
        int bb = row / Nn, nn = row - bb * Nn;
        size_t oi = ((size_t)bb * TOUT + n) * Nn + nn;
        float ov = (s[r] + bz) * sc + sh;
        if (fl) ((float*)outp)[oi] = ov;
        else    ((ush*)outp)[oi] = f2bu(ov);
      }
    }
  }
}

}  // namespace

extern "C" void kernel_launch(void* const* d_in, const int* in_sizes, int n_in,
                              void* d_out, int out_size, void* d_ws, size_t ws_size,
                              hipStream_t stream) {
  float* f = (float*)d_ws;
  int* flag = (int*)d_ws;                 // f[0..15]
  float* CS  = f + 16;                    // 1020 small params (f32)
  float* xT  = f + 1040;                  // 147456
  float* sd  = f + 148496;                // 12288
  float* psf = f + 160784;                // 8*12288*16 = 1572864
  float* psb = f + 1733648;               // 1572864
  ush* U = (ush*)(f + 3306512);
  ush* pA    = U;                         // 12288*32
  ush* lA    = U + 393216;                // 12288*32
  ush* Pk    = U + 786432;                // 12288*64 packed b-frags
  ush* Xc    = U + 1572864;               // 8*16*1536
  ush* Wf    = U + 1769472;               // 199680

  SmallTab st;
  {
    const int idxs[16] = {1, 2, 4, 6, 8, 10, 11, 12, 13, 15, 17, 19, 21, 22, 23, 24};
    const int ns[16]   = {64, 64, 128, 128, 64, 64, 64, 64, 64, 128, 128, 12, 12, 12, 12, 12};
    int off = 0;
    for (int i = 0; i < 16; ++i) {
      st.src[i] = d_in[idxs[i]]; st.n[i] = ns[i]; st.off[i] = off; off += ns[i];
    }
  }
  RepTab rt;
  {
    const int idxs[8]  = {3, 5, 7, 9, 14, 16, 18, 20};
    const int rNc[8]   = {128, 128, 64, 64, 128, 128, 12, 12};
    const int rNCT[8]  = {8, 8, 4, 4, 8, 8, 1, 1};
    const int rlb[9]   = {0, 12288, 14336, 15360, 21504, 22528, 24576, 24832, 24960};
    for (int i = 0; i < 8; ++i) {
      rt.src[i] = d_in[idxs[i]]; rt.Nc[i] = rNc[i]; rt.NCT[i] = rNCT[i];
    }
    for (int i = 0; i < 9; ++i) rt.lb[i] = rlb[i];
  }

  prep_all<<<147, 256, 0, stream>>>(d_in[0], st, rt, flag, CS, xT, sd,
                                    pA, lA, Pk, Xc, Wf);
  kl_mfma<<<1536, 256, 0, stream>>>(pA, lA, Pk, Xc, sd, psf, psb);
  fused_mlp<<<384, 512, 0, stream>>>(xT, psf, psb, CS, Wf, flag, d_out);
}